// Round 5
// baseline (7281.698 us; speedup 1.0000x reference)
//
#include <hip/hip_runtime.h>

// ---------------------------------------------------------------------------
// CUBA spiking CNN, forward only.
// Numerics contract (match a canonical numpy fp32 trajectory):
//   * every dot/conv = ONE fp32 accumulator per output, sequential fmaf
//     chain in ascending k-order ((c,i,j) for convs, 0..K-1 for matmuls)
//   * bias added AFTER the sum (reference association), unfused
//   * all elementwise/LIF ops unfused fp32 (__fmul_rn/__fadd_rn; no FMA
//     contraction — numpy ufuncs don't contract)
//   * spikes stored u8 (exact), pooled values exact multiples of 0.25
// Front-end conv1/conv2/pool/conv3 time-chunked (TCF from ws_size);
// back-end tc/fc1 chunked at TCB=50.
// ---------------------------------------------------------------------------

#define B_   64
#define T_   200
#define TCB_ 50

__device__ __forceinline__ void lif32(float psp, float& cur, float& volt, float& spk) {
#pragma clang fp contract(off)
    cur  = __fadd_rn(__fmul_rn(0.5f, cur), psp);
    volt = __fadd_rn(__fmul_rn(__fmul_rn(0.75f, volt), __fsub_rn(1.0f, spk)), cur);
    spk  = (volt > 0.5f) ? 1.0f : 0.0f;
}

// ---------------------------------------------------------------------------
// K0: weight transposes (fp32). dst[k*N+o] = src[o*K+k]
// ---------------------------------------------------------------------------
__global__ void k_setup(const float* __restrict__ w2, const float* __restrict__ w3,
                        const float* __restrict__ tcw, const float* __restrict__ recw,
                        const float* __restrict__ fw,
                        float* __restrict__ w2T, float* __restrict__ w3T,
                        float* __restrict__ tcT, float* __restrict__ recT,
                        float* __restrict__ fc1T) {
    int idx = blockIdx.x * 256 + threadIdx.x;
    if (idx < 73728) { int o = idx & 127, k = idx >> 7; w2T[idx] = w2[o * 576 + k]; return; }
    idx -= 73728;
    if (idx < 294912) { int o = idx & 255, k = idx >> 8; w3T[idx] = w3[o * 1152 + k]; return; }
    idx -= 294912;
    if (idx < 196608) { int tap = idx >> 16, r = idx & 65535; int o = r & 255, k = r >> 8;
                        tcT[idx] = tcw[tap * 65536 + o * 256 + k]; return; }
    idx -= 196608;
    if (idx < 65536) { int o = idx & 255, k = idx >> 8; recT[idx] = recw[o * 256 + k]; return; }
    idx -= 65536;
    if (idx < 32768) { int o = idx & 127, k = idx >> 7; fc1T[idx] = fw[o * 256 + k]; return; }
}

// ---------------------------------------------------------------------------
// K1: conv1 (1->64, 3x3, 10x10->8x8) + LIF1, one chunk. Sequential fp32
// fmaf over (i,j); psp = sum + bias (unfused). States fp32 in st1.
// ---------------------------------------------------------------------------
__global__ __launch_bounds__(256) void k_conv1(const float* __restrict__ x,
                                               const float* __restrict__ w1,
                                               const float* __restrict__ b1,
                                               unsigned char* __restrict__ s1c,
                                               float* __restrict__ st1,
                                               int t0, int TC, int first) {
    int idx = blockIdx.x * 256 + threadIdx.x;   // 262144
    int xx = idx & 7, yy = (idx >> 3) & 7, o = (idx >> 6) & 63, b = idx >> 12;
    float w[9];
#pragma unroll
    for (int i = 0; i < 9; i++) w[i] = w1[o * 9 + i];
    float bias = b1[o];
    const float* xb = x + (size_t)b * 20000;
    unsigned char* sb = s1c + (size_t)b * TC * 4096 + (o << 6) + (yy << 3) + xx;
    float cur, volt, spk;
    if (first) { cur = 0.f; volt = 0.f; spk = 0.f; }
    else { cur = st1[idx]; volt = st1[262144 + idx]; spk = st1[524288 + idx]; }
    for (int tl = 0; tl < TC; tl += 4) {
        int t = t0 + tl;
        float a0 = 0.f, a1 = 0.f, a2 = 0.f, a3 = 0.f;
#pragma unroll
        for (int i = 0; i < 3; i++) {
#pragma unroll
            for (int j = 0; j < 3; j++) {
                float4 v = *(const float4*)&xb[((yy + i) * 10 + xx + j) * T_ + t];
                float wv = w[i * 3 + j];
                a0 = fmaf(wv, v.x, a0); a1 = fmaf(wv, v.y, a1);
                a2 = fmaf(wv, v.z, a2); a3 = fmaf(wv, v.w, a3);
            }
        }
        float accs[4] = {a0, a1, a2, a3};
#pragma unroll
        for (int q = 0; q < 4; q++) {
            float psp = __fadd_rn(accs[q], bias);
            lif32(psp, cur, volt, spk);
            sb[(size_t)(tl + q) * 4096] = (unsigned char)spk;
        }
    }
    st1[idx] = cur; st1[262144 + idx] = volt; st1[524288 + idx] = spk;
}

// ---------------------------------------------------------------------------
// K2: conv2 (64->128, 3x3, 8x8->6x6), WG per (b,tl). One fp32 accumulator
// per output, sequential fmaf in (c,i,j) order; +bias after (unfused).
// ---------------------------------------------------------------------------
__global__ __launch_bounds__(192) void k_conv2(const unsigned char* __restrict__ s1c,
                                               const float* __restrict__ w2T,
                                               const float* __restrict__ b2,
                                               float* __restrict__ psp2c) {
    __shared__ float a_s[4096];                 // [c=64][y=8][x=8]
    int blk = blockIdx.x;                       // b*TC + tl
    int tid = threadIdx.x;
    const unsigned int* src4 = (const unsigned int*)(s1c + (size_t)blk * 4096);
    for (int i = tid; i < 1024; i += 192) {
        unsigned int u = src4[i];
        a_s[4 * i + 0] = (float)(u & 0xff);
        a_s[4 * i + 1] = (float)((u >> 8) & 0xff);
        a_s[4 * i + 2] = (float)((u >> 16) & 0xff);
        a_s[4 * i + 3] = (float)(u >> 24);
    }
    __syncthreads();
    int quad = tid / 6;                         // 0..31
    int y = tid - quad * 6;                     // 0..5
    int ob = quad << 2;
    float acc[4][6];
#pragma unroll
    for (int oo = 0; oo < 4; oo++)
#pragma unroll
        for (int xq = 0; xq < 6; xq++) acc[oo][xq] = 0.f;
    for (int c = 0; c < 64; c++) {
#pragma unroll
        for (int i = 0; i < 3; i++) {
            const float* ar = &a_s[c * 64 + (y + i) * 8];
            float4 f0 = *(const float4*)(ar);
            float4 f1 = *(const float4*)(ar + 4);
            float a[8] = {f0.x, f0.y, f0.z, f0.w, f1.x, f1.y, f1.z, f1.w};
            const float* wr = w2T + (size_t)((c * 3 + i) * 3) * 128 + ob;
#pragma unroll
            for (int j = 0; j < 3; j++) {
                float4 wv = *(const float4*)(wr + j * 128);
                float w4[4] = {wv.x, wv.y, wv.z, wv.w};
#pragma unroll
                for (int oo = 0; oo < 4; oo++)
#pragma unroll
                    for (int xq = 0; xq < 6; xq++)
                        acc[oo][xq] = fmaf(w4[oo], a[xq + j], acc[oo][xq]);
            }
        }
    }
    size_t obase = (size_t)blk * 4608 + (size_t)ob * 36 + y * 6;
#pragma unroll
    for (int oo = 0; oo < 4; oo++) {
        float bv = b2[ob + oo];
        float* dst = psp2c + obase + oo * 36;
#pragma unroll
        for (int xq = 0; xq < 6; xq++)
            dst[xq] = __fadd_rn(acc[oo][xq], bv);
    }
}

// ---------------------------------------------------------------------------
// K3: LIF2 + AvgPool(2), fp32 states (12 planes x 73728 in st2), chunk.
// pc: fp32 [b*TC+tl][1152] (exact multiples of 0.25).
// ---------------------------------------------------------------------------
__global__ __launch_bounds__(256) void k_lif2pool(const float* __restrict__ psp2c,
                                                  float* __restrict__ pc,
                                                  float* __restrict__ st2,
                                                  int TC, int first) {
    int idx = blockIdx.x * 256 + threadIdx.x;   // 73728
    int px = idx % 3; int r = idx / 3; int py = r % 3; r /= 3;
    int o = r & 127, b = r >> 7;
    const float* pb = psp2c + (size_t)b * TC * 4608 + o * 36;
    float* pd = pc + (size_t)b * TC * 1152 + o * 9 + py * 3 + px;
    int off0 = (2 * py) * 6 + 2 * px, off1 = off0 + 6;
    float c0, c1, c2, c3, v0, v1, v2, v3, s0, s1, s2, s3;
    if (first) {
        c0 = c1 = c2 = c3 = v0 = v1 = v2 = v3 = s0 = s1 = s2 = s3 = 0.f;
    } else {
        c0 = st2[idx];              c1 = st2[73728 + idx];
        c2 = st2[147456 + idx];     c3 = st2[221184 + idx];
        v0 = st2[294912 + idx];     v1 = st2[368640 + idx];
        v2 = st2[442368 + idx];     v3 = st2[516096 + idx];
        s0 = st2[589824 + idx];     s1 = st2[663552 + idx];
        s2 = st2[737280 + idx];     s3 = st2[811008 + idx];
    }
    for (int tl = 0; tl < TC; tl++) {
        const float* pt = pb + (size_t)tl * 4608;
        float2 ra = *(const float2*)(pt + off0);
        float2 rb = *(const float2*)(pt + off1);
        lif32(ra.x, c0, v0, s0);
        lif32(ra.y, c1, v1, s1);
        lif32(rb.x, c2, v2, s2);
        lif32(rb.y, c3, v3, s3);
        // sum of 0/1 values: exact in any order; *0.25 exact
        pd[(size_t)tl * 1152] = __fmul_rn(0.25f, __fadd_rn(__fadd_rn(__fadd_rn(s0, s1), s2), s3));
    }
    st2[idx] = c0;           st2[73728 + idx] = c1;
    st2[147456 + idx] = c2;  st2[221184 + idx] = c3;
    st2[294912 + idx] = v0;  st2[368640 + idx] = v1;
    st2[442368 + idx] = v2;  st2[516096 + idx] = v3;
    st2[589824 + idx] = s0;  st2[663552 + idx] = s1;
    st2[737280 + idx] = s2;  st2[811008 + idx] = s3;
}

// ---------------------------------------------------------------------------
// K4: conv3 GEMM rows x 256, K=1152 (ascending, sequential fp32 fmaf),
// K-chunked LDS (16x288 fp32). Epilogue: +bias unfused.
// ---------------------------------------------------------------------------
__global__ __launch_bounds__(256) void k_conv3(const float* __restrict__ pc,
                                               const float* __restrict__ w3T,
                                               const float* __restrict__ b3,
                                               float* __restrict__ psp3c) {
    __shared__ float a_s[16 * 288];
    int row0 = blockIdx.x * 16;
    int tid = threadIdx.x;
    int oq = tid & 63, mg = tid >> 6;
    float acc[4][4];
#pragma unroll
    for (int oo = 0; oo < 4; oo++)
#pragma unroll
        for (int mi = 0; mi < 4; mi++) acc[oo][mi] = 0.f;
    for (int kc = 0; kc < 1152; kc += 288) {
        __syncthreads();
        for (int idx = tid; idx < 16 * 288; idx += 256) {
            int m = idx / 288, k = idx - m * 288;
            a_s[idx] = pc[(size_t)(row0 + m) * 1152 + kc + k];
        }
        __syncthreads();
        for (int k = 0; k < 288; k++) {
            float4 wv = *(const float4*)&w3T[(size_t)(kc + k) * 256 + (oq << 2)];
            float w4[4] = {wv.x, wv.y, wv.z, wv.w};
            float am[4];
#pragma unroll
            for (int mi = 0; mi < 4; mi++) am[mi] = a_s[(mg * 4 + mi) * 288 + k];
#pragma unroll
            for (int oo = 0; oo < 4; oo++)
#pragma unroll
                for (int mi = 0; mi < 4; mi++)
                    acc[oo][mi] = fmaf(w4[oo], am[mi], acc[oo][mi]);
        }
    }
#pragma unroll
    for (int mi = 0; mi < 4; mi++) {
        float* dst = psp3c + (size_t)(row0 + mg * 4 + mi) * 256 + (oq << 2);
#pragma unroll
        for (int oo = 0; oo < 4; oo++)
            dst[oo] = __fadd_rn(acc[oo][mi], b3[(oq << 2) + oo]);
    }
}

// ---------------------------------------------------------------------------
// K5: LIF3 scan on chunk, fp32 states (st3), writes u8 s3u8[b][t][256].
// ---------------------------------------------------------------------------
__global__ __launch_bounds__(256) void k_scan3(const float* __restrict__ psp3c,
                                               unsigned char* __restrict__ s3u8,
                                               float* __restrict__ st3,
                                               int t0, int TC, int first) {
    int idx = blockIdx.x * 256 + threadIdx.x;   // 16384
    int b = idx >> 8, n = idx & 255;
    float cur, volt, spk;
    if (first) { cur = 0.f; volt = 0.f; spk = 0.f; }
    else { cur = st3[idx]; volt = st3[16384 + idx]; spk = st3[32768 + idx]; }
    for (int tl = 0; tl < TC; tl++) {
        lif32(psp3c[(size_t)(b * TC + tl) * 256 + n], cur, volt, spk);
        s3u8[((size_t)b * T_ + t0 + tl) * 256 + n] = (unsigned char)spk;
    }
    st3[idx] = cur; st3[16384 + idx] = volt; st3[32768 + idx] = spk;
}

// ---------------------------------------------------------------------------
// K6: temporal conv, back-end chunk TCB=50. Per tap: sequential fp32 dot
// (k=0..255) -> +bias (unfused) -> gated sequential psum (numpy order).
// ---------------------------------------------------------------------------
__global__ __launch_bounds__(256) void k_tc(const unsigned char* __restrict__ s3u8,
                                            const float* __restrict__ tcT,
                                            const float* __restrict__ tc_b,
                                            float* __restrict__ ptcc, int t0) {
    __shared__ float a_s[16 * 256];
    int crow0 = blockIdx.x * 16;
    int tid = threadIdx.x;
    int oq = tid & 63, mg = tid >> 6;
    float psum[4][4];
#pragma unroll
    for (int oo = 0; oo < 4; oo++)
#pragma unroll
        for (int mi = 0; mi < 4; mi++) psum[oo][mi] = 0.f;
    for (int tap = 0; tap < 3; tap++) {
        __syncthreads();
        for (int idx = tid; idx < 16 * 256; idx += 256) {
            int m = idx >> 8, k = idx & 255;
            int crow = crow0 + m;
            int b = crow / TCB_, tl = crow - b * TCB_;
            int t = t0 + tl;
            float v = 0.f;
            if (t >= tap) v = (float)s3u8[((size_t)b * T_ + t - tap) * 256 + k];
            a_s[idx] = v;
        }
        __syncthreads();
        float acc[4][4];
#pragma unroll
        for (int oo = 0; oo < 4; oo++)
#pragma unroll
            for (int mi = 0; mi < 4; mi++) acc[oo][mi] = 0.f;
        const float* wbase = tcT + (size_t)tap * 65536 + (oq << 2);
        for (int k = 0; k < 256; k++) {
            float4 wv = *(const float4*)(wbase + (size_t)k * 256);
            float w4[4] = {wv.x, wv.y, wv.z, wv.w};
            float am[4];
#pragma unroll
            for (int mi = 0; mi < 4; mi++) am[mi] = a_s[(mg * 4 + mi) * 256 + k];
#pragma unroll
            for (int oo = 0; oo < 4; oo++)
#pragma unroll
                for (int mi = 0; mi < 4; mi++)
                    acc[oo][mi] = fmaf(w4[oo], am[mi], acc[oo][mi]);
        }
#pragma unroll
        for (int mi = 0; mi < 4; mi++) {
            int crow = crow0 + mg * 4 + mi;
            int b = crow / TCB_, tl = crow - b * TCB_;
            int t = t0 + tl;
            float g = (t >= tap) ? 1.0f : 0.0f;
#pragma unroll
            for (int oo = 0; oo < 4; oo++) {
                int oc = (oq << 2) + oo;
                float tap_f = __fadd_rn(acc[oo][mi], tc_b[tap * 256 + oc]);
                psum[oo][mi] = __fadd_rn(psum[oo][mi], __fmul_rn(g, tap_f));
            }
        }
    }
#pragma unroll
    for (int mi = 0; mi < 4; mi++) {
        int crow = crow0 + mg * 4 + mi;
        float* dst = ptcc + (size_t)crow * 256 + (oq << 2);
#pragma unroll
        for (int oo = 0; oo < 4; oo++) dst[oo] = psum[oo][mi];
    }
}

// ---------------------------------------------------------------------------
// K7: LIF scan for tc layer, back-end chunk, fp32 states st_tc.
// ---------------------------------------------------------------------------
__global__ __launch_bounds__(256) void k_scan_tc(const float* __restrict__ ptcc,
                                                 unsigned char* __restrict__ s_tc8,
                                                 float* __restrict__ st_tc,
                                                 int t0, int first) {
    int idx = blockIdx.x * 256 + threadIdx.x;   // 16384
    int b = idx >> 8, n = idx & 255;
    float cur, volt, spk;
    if (first) { cur = 0.f; volt = 0.f; spk = 0.f; }
    else { cur = st_tc[idx]; volt = st_tc[16384 + idx]; spk = st_tc[32768 + idx]; }
    for (int tl = 0; tl < TCB_; tl++) {
        lif32(ptcc[(size_t)(b * TCB_ + tl) * 256 + n], cur, volt, spk);
        s_tc8[((size_t)b * T_ + t0 + tl) * 256 + n] = (unsigned char)spk;
    }
    st_tc[idx] = cur; st_tc[16384 + idx] = volt; st_tc[32768 + idx] = spk;
}

// ---------------------------------------------------------------------------
// K8: recurrent layer. WG per batch element; prev spikes in LDS. Sequential
// fp32 sum over k (skipping zero spikes is EXACT: acc+0==acc);
// psp = (s_tc + mat) + rec_b unfused (numpy order).
// ---------------------------------------------------------------------------
__global__ __launch_bounds__(256) void k_rec(const unsigned char* __restrict__ s_tc8,
                                             const float* __restrict__ recT,
                                             const float* __restrict__ rec_b,
                                             unsigned char* __restrict__ s_r8) {
    __shared__ float spk_s[256];
    int b = blockIdx.x, o = threadIdx.x;
    spk_s[o] = 0.f;
    float cur = 0.f, volt = 0.f, spk = 0.f;
    float rb = rec_b[o];
    __syncthreads();
    for (int t = 0; t < T_; t++) {
        float acc = 0.f;
#pragma unroll 4
        for (int k = 0; k < 256; k++) {
            float sv = spk_s[k];
            if (sv != 0.f) acc = __fadd_rn(acc, recT[(size_t)k * 256 + o]);
        }
        float stc = (float)s_tc8[((size_t)b * T_ + t) * 256 + o];
        float psp = __fadd_rn(__fadd_rn(stc, acc), rb);
        lif32(psp, cur, volt, spk);
        s_r8[((size_t)b * T_ + t) * 256 + o] = (unsigned char)spk;
        __syncthreads();
        spk_s[o] = spk;
        __syncthreads();
    }
}

// ---------------------------------------------------------------------------
// K9: fc1 GEMM, back-end chunk. Sequential fp32 fmaf k=0..255; +bias after.
// ---------------------------------------------------------------------------
__global__ __launch_bounds__(256) void k_fc1(const unsigned char* __restrict__ s_r8,
                                             const float* __restrict__ fc1T,
                                             const float* __restrict__ fc1_b,
                                             float* __restrict__ pfc, int t0) {
    __shared__ float a_s[16 * 256];
    int crow0 = blockIdx.x * 16;
    int tid = threadIdx.x;
    int oq = tid & 31, mg = tid >> 5;           // 8 m-groups, tile 2m
    float acc[4][2];
#pragma unroll
    for (int oo = 0; oo < 4; oo++) { acc[oo][0] = 0.f; acc[oo][1] = 0.f; }
    for (int idx = tid; idx < 16 * 256; idx += 256) {
        int m = idx >> 8, k = idx & 255;
        int crow = crow0 + m;
        int b = crow / TCB_, tl = crow - b * TCB_;
        a_s[idx] = (float)s_r8[((size_t)b * T_ + t0 + tl) * 256 + k];
    }
    __syncthreads();
    for (int k = 0; k < 256; k++) {
        float4 wv = *(const float4*)&fc1T[(size_t)k * 128 + (oq << 2)];
        float w4[4] = {wv.x, wv.y, wv.z, wv.w};
        float a0 = a_s[(mg * 2 + 0) * 256 + k];
        float a1 = a_s[(mg * 2 + 1) * 256 + k];
#pragma unroll
        for (int oo = 0; oo < 4; oo++) {
            acc[oo][0] = fmaf(w4[oo], a0, acc[oo][0]);
            acc[oo][1] = fmaf(w4[oo], a1, acc[oo][1]);
        }
    }
#pragma unroll
    for (int mi = 0; mi < 2; mi++) {
        float* dst = pfc + (size_t)(crow0 + mg * 2 + mi) * 128 + (oq << 2);
#pragma unroll
        for (int oo = 0; oo < 4; oo++)
            dst[oo] = __fadd_rn(acc[oo][mi], fc1_b[(oq << 2) + oo]);
    }
}

// ---------------------------------------------------------------------------
// K10: LIF scan for fc1 layer, back-end chunk, fp32 states st_f.
// ---------------------------------------------------------------------------
__global__ __launch_bounds__(256) void k_scan_f(const float* __restrict__ pfc,
                                                unsigned char* __restrict__ s_f8,
                                                float* __restrict__ st_f,
                                                int t0, int first) {
    int idx = blockIdx.x * 256 + threadIdx.x;   // 8192
    int b = idx >> 7, n = idx & 127;
    float cur, volt, spk;
    if (first) { cur = 0.f; volt = 0.f; spk = 0.f; }
    else { cur = st_f[idx]; volt = st_f[8192 + idx]; spk = st_f[16384 + idx]; }
    for (int tl = 0; tl < TCB_; tl++) {
        lif32(pfc[(size_t)(b * TCB_ + tl) * 128 + n], cur, volt, spk);
        s_f8[((size_t)b * T_ + t0 + tl) * 128 + n] = (unsigned char)spk;
    }
    st_f[idx] = cur; st_f[8192 + idx] = volt; st_f[16384 + idx] = spk;
}

// ---------------------------------------------------------------------------
// K11: out[b,:] = fc2_w @ (sum_t ts[t]*s_f[b,t,:]) — linear head, fp64
// accumulation (differences ~1e-7 are far below the bf16 floor).
// ---------------------------------------------------------------------------
__global__ __launch_bounds__(128) void k_final(const unsigned char* __restrict__ s_f8,
                                               const float* __restrict__ ts,
                                               const float* __restrict__ fc2,
                                               float* __restrict__ out) {
    __shared__ double q_s[128];
    int b = blockIdx.x, k = threadIdx.x;
    double q = 0.0;
    const unsigned char* sf = s_f8 + (size_t)b * T_ * 128 + k;
    for (int t = 0; t < T_; t++) q = fma((double)ts[t], (double)sf[(size_t)t * 128], q);
    q_s[k] = q;
    __syncthreads();
    if (k < 2) {
        double o = 0.0;
        for (int kk = 0; kk < 128; kk++) o = fma((double)fc2[k * 128 + kk], q_s[kk], o);
        out[b * 2 + k] = (float)o;
    }
}

// ---------------------------------------------------------------------------
extern "C" void kernel_launch(void* const* d_in, const int* in_sizes, int n_in,
                              void* d_out, int out_size, void* d_ws, size_t ws_size,
                              hipStream_t stream) {
    const float* x       = (const float*)d_in[0];
    const float* conv1_w = (const float*)d_in[1];
    const float* conv1_b = (const float*)d_in[2];
    const float* conv2_w = (const float*)d_in[3];
    const float* conv2_b = (const float*)d_in[4];
    const float* conv3_w = (const float*)d_in[5];
    const float* conv3_b = (const float*)d_in[6];
    const float* tc_w    = (const float*)d_in[7];
    const float* tc_b    = (const float*)d_in[8];
    const float* rec_w   = (const float*)d_in[9];
    const float* rec_b   = (const float*)d_in[10];
    const float* fc1_w   = (const float*)d_in[11];
    const float* fc1_b   = (const float*)d_in[12];
    const float* fc2_w   = (const float*)d_in[13];
    const float* ts_w    = (const float*)d_in[14];
    float* out = (float*)d_out;
    (void)in_sizes; (void)n_in; (void)out_size;

    // ---- persistent region: 21,299,200 B ----
    char* base = (char*)d_ws;
    float* w2T  = (float*)(base + 0);           //   294,912 B
    float* w3T  = (float*)(base + 294912);      // 1,179,648 B
    float* tcT  = (float*)(base + 1474560);     //   786,432 B
    float* recT = (float*)(base + 2260992);     //   262,144 B
    float* fc1T = (float*)(base + 2523136);     //   131,072 B
    float* st1  = (float*)(base + 2654208);     // 3,145,728 B
    float* st2  = (float*)(base + 5799936);     // 3,538,944 B
    float* st3  = (float*)(base + 9338880);     //   196,608 B
    float* st_tc= (float*)(base + 9535488);     //   196,608 B
    float* st_f = (float*)(base + 9732096);     //    98,304 B
    unsigned char* s3u8  = (unsigned char*)(base + 9830400);   // 3,276,800 B
    unsigned char* s_tc8 = (unsigned char*)(base + 13107200);  // 3,276,800 B
    unsigned char* s_r8  = (unsigned char*)(base + 16384000);  // 3,276,800 B
    unsigned char* s_f8  = (unsigned char*)(base + 19660800);  // 1,638,400 B

    // ---- chunked scratch region, TCF chosen from ws_size (graph-safe) ----
    const size_t PERS = 21299200;
    const size_t PER_T = 1802240;   // bytes per front-end timestep (B=64)
    int TCF;
    if      (ws_size >= PERS + 40 * PER_T) TCF = 40;
    else if (ws_size >= PERS + 20 * PER_T) TCF = 20;
    else if (ws_size >= PERS +  8 * PER_T) TCF = 8;   // 35.7 MB — proven fit
    else                                   TCF = 4;
    int NCH = T_ / TCF;
    char* cb = base + PERS;
    float* psp2c = (float*)(cb);                                      // TCF*1,179,648 B
    float* psp3c = (float*)(cb + (size_t)TCF * 1179648);              // TCF*65,536 B
    float* pc    = (float*)(cb + (size_t)TCF * (1179648 + 65536));    // TCF*294,912 B
    unsigned char* s1c = (unsigned char*)(cb + (size_t)TCF * (1179648 + 65536 + 294912)); // TCF*262,144 B
    // back-end chunk buffers alias the front-end scratch (dead by then)
    float* ptcc = (float*)(cb);              // 3,276,800 B
    float* pfc  = (float*)(cb + 3276800);    // 1,638,400 B

    k_setup<<<2592, 256, 0, stream>>>(conv2_w, conv3_w, tc_w, rec_w, fc1_w,
                                      w2T, w3T, tcT, recT, fc1T);
    for (int ch = 0; ch < NCH; ch++) {
        int t0 = ch * TCF;
        int first = (ch == 0) ? 1 : 0;
        k_conv1<<<1024, 256, 0, stream>>>(x, conv1_w, conv1_b, s1c, st1, t0, TCF, first);
        k_conv2<<<B_ * TCF, 192, 0, stream>>>(s1c, w2T, conv2_b, psp2c);
        k_lif2pool<<<288, 256, 0, stream>>>(psp2c, pc, st2, TCF, first);
        k_conv3<<<B_ * TCF / 16, 256, 0, stream>>>(pc, w3T, conv3_b, psp3c);
        k_scan3<<<64, 256, 0, stream>>>(psp3c, s3u8, st3, t0, TCF, first);
    }
    for (int bc = 0; bc < T_ / TCB_; bc++) {
        int t0 = bc * TCB_;
        k_tc<<<B_ * TCB_ / 16, 256, 0, stream>>>(s3u8, tcT, tc_b, ptcc, t0);
        k_scan_tc<<<64, 256, 0, stream>>>(ptcc, s_tc8, st_tc, t0, (bc == 0) ? 1 : 0);
    }
    k_rec<<<64, 256, 0, stream>>>(s_tc8, recT, rec_b, s_r8);
    for (int bc = 0; bc < T_ / TCB_; bc++) {
        int t0 = bc * TCB_;
        k_fc1<<<B_ * TCB_ / 16, 256, 0, stream>>>(s_r8, fc1T, fc1_b, pfc, t0);
        k_scan_f<<<32, 256, 0, stream>>>(pfc, s_f8, st_f, t0, (bc == 0) ? 1 : 0);
    }
    k_final<<<64, 128, 0, stream>>>(s_f8, ts_w, fc2_w, out);
}

// Round 6
// 3084.526 us; speedup vs baseline: 2.3607x; 2.3607x over previous
//
#include <hip/hip_runtime.h>

// ---------------------------------------------------------------------------
// CUBA spiking CNN, forward only.
// Numerics contract (match a canonical numpy fp32 trajectory):
//   * every dot/conv = ONE fp32 accumulator per output, sequential fmaf
//     chain in ascending k-order ((c,i,j) for convs, 0..K-1 for matmuls)
//   * bias added AFTER the sum (reference association), unfused
//   * all elementwise/LIF ops unfused fp32 (__fmul_rn/__fadd_rn; no FMA
//     contraction — numpy ufuncs don't contract)
//   * spikes stored u8 (exact), pooled values exact multiples of 0.25
// Front-end conv1/conv2/pool/conv3 time-chunked (TCF from ws_size);
// back-end tc/fc1 chunked at TCB=50.
// R6: k_rec inner loop made branchless (acc + (sv?w:0) is bit-identical to
// the skip version) so loads pipeline; single barrier/step via double buffer.
// ---------------------------------------------------------------------------

#define B_   64
#define T_   200
#define TCB_ 50

__device__ __forceinline__ void lif32(float psp, float& cur, float& volt, float& spk) {
#pragma clang fp contract(off)
    cur  = __fadd_rn(__fmul_rn(0.5f, cur), psp);
    volt = __fadd_rn(__fmul_rn(__fmul_rn(0.75f, volt), __fsub_rn(1.0f, spk)), cur);
    spk  = (volt > 0.5f) ? 1.0f : 0.0f;
}

// ---------------------------------------------------------------------------
// K0: weight transposes (fp32). dst[k*N+o] = src[o*K+k]
// ---------------------------------------------------------------------------
__global__ void k_setup(const float* __restrict__ w2, const float* __restrict__ w3,
                        const float* __restrict__ tcw, const float* __restrict__ recw,
                        const float* __restrict__ fw,
                        float* __restrict__ w2T, float* __restrict__ w3T,
                        float* __restrict__ tcT, float* __restrict__ recT,
                        float* __restrict__ fc1T) {
    int idx = blockIdx.x * 256 + threadIdx.x;
    if (idx < 73728) { int o = idx & 127, k = idx >> 7; w2T[idx] = w2[o * 576 + k]; return; }
    idx -= 73728;
    if (idx < 294912) { int o = idx & 255, k = idx >> 8; w3T[idx] = w3[o * 1152 + k]; return; }
    idx -= 294912;
    if (idx < 196608) { int tap = idx >> 16, r = idx & 65535; int o = r & 255, k = r >> 8;
                        tcT[idx] = tcw[tap * 65536 + o * 256 + k]; return; }
    idx -= 196608;
    if (idx < 65536) { int o = idx & 255, k = idx >> 8; recT[idx] = recw[o * 256 + k]; return; }
    idx -= 65536;
    if (idx < 32768) { int o = idx & 127, k = idx >> 7; fc1T[idx] = fw[o * 256 + k]; return; }
}

// ---------------------------------------------------------------------------
// K1: conv1 (1->64, 3x3, 10x10->8x8) + LIF1, one chunk. Sequential fp32
// fmaf over (i,j); psp = sum + bias (unfused). States fp32 in st1.
// ---------------------------------------------------------------------------
__global__ __launch_bounds__(256) void k_conv1(const float* __restrict__ x,
                                               const float* __restrict__ w1,
                                               const float* __restrict__ b1,
                                               unsigned char* __restrict__ s1c,
                                               float* __restrict__ st1,
                                               int t0, int TC, int first) {
    int idx = blockIdx.x * 256 + threadIdx.x;   // 262144
    int xx = idx & 7, yy = (idx >> 3) & 7, o = (idx >> 6) & 63, b = idx >> 12;
    float w[9];
#pragma unroll
    for (int i = 0; i < 9; i++) w[i] = w1[o * 9 + i];
    float bias = b1[o];
    const float* xb = x + (size_t)b * 20000;
    unsigned char* sb = s1c + (size_t)b * TC * 4096 + (o << 6) + (yy << 3) + xx;
    float cur, volt, spk;
    if (first) { cur = 0.f; volt = 0.f; spk = 0.f; }
    else { cur = st1[idx]; volt = st1[262144 + idx]; spk = st1[524288 + idx]; }
    for (int tl = 0; tl < TC; tl += 4) {
        int t = t0 + tl;
        float a0 = 0.f, a1 = 0.f, a2 = 0.f, a3 = 0.f;
#pragma unroll
        for (int i = 0; i < 3; i++) {
#pragma unroll
            for (int j = 0; j < 3; j++) {
                float4 v = *(const float4*)&xb[((yy + i) * 10 + xx + j) * T_ + t];
                float wv = w[i * 3 + j];
                a0 = fmaf(wv, v.x, a0); a1 = fmaf(wv, v.y, a1);
                a2 = fmaf(wv, v.z, a2); a3 = fmaf(wv, v.w, a3);
            }
        }
        float accs[4] = {a0, a1, a2, a3};
#pragma unroll
        for (int q = 0; q < 4; q++) {
            float psp = __fadd_rn(accs[q], bias);
            lif32(psp, cur, volt, spk);
            sb[(size_t)(tl + q) * 4096] = (unsigned char)spk;
        }
    }
    st1[idx] = cur; st1[262144 + idx] = volt; st1[524288 + idx] = spk;
}

// ---------------------------------------------------------------------------
// K2: conv2 (64->128, 3x3, 8x8->6x6), WG per (b,tl). One fp32 accumulator
// per output, sequential fmaf in (c,i,j) order; +bias after (unfused).
// ---------------------------------------------------------------------------
__global__ __launch_bounds__(192) void k_conv2(const unsigned char* __restrict__ s1c,
                                               const float* __restrict__ w2T,
                                               const float* __restrict__ b2,
                                               float* __restrict__ psp2c) {
    __shared__ float a_s[4096];                 // [c=64][y=8][x=8]
    int blk = blockIdx.x;                       // b*TC + tl
    int tid = threadIdx.x;
    const unsigned int* src4 = (const unsigned int*)(s1c + (size_t)blk * 4096);
    for (int i = tid; i < 1024; i += 192) {
        unsigned int u = src4[i];
        a_s[4 * i + 0] = (float)(u & 0xff);
        a_s[4 * i + 1] = (float)((u >> 8) & 0xff);
        a_s[4 * i + 2] = (float)((u >> 16) & 0xff);
        a_s[4 * i + 3] = (float)(u >> 24);
    }
    __syncthreads();
    int quad = tid / 6;                         // 0..31
    int y = tid - quad * 6;                     // 0..5
    int ob = quad << 2;
    float acc[4][6];
#pragma unroll
    for (int oo = 0; oo < 4; oo++)
#pragma unroll
        for (int xq = 0; xq < 6; xq++) acc[oo][xq] = 0.f;
    for (int c = 0; c < 64; c++) {
#pragma unroll
        for (int i = 0; i < 3; i++) {
            const float* ar = &a_s[c * 64 + (y + i) * 8];
            float4 f0 = *(const float4*)(ar);
            float4 f1 = *(const float4*)(ar + 4);
            float a[8] = {f0.x, f0.y, f0.z, f0.w, f1.x, f1.y, f1.z, f1.w};
            const float* wr = w2T + (size_t)((c * 3 + i) * 3) * 128 + ob;
#pragma unroll
            for (int j = 0; j < 3; j++) {
                float4 wv = *(const float4*)(wr + j * 128);
                float w4[4] = {wv.x, wv.y, wv.z, wv.w};
#pragma unroll
                for (int oo = 0; oo < 4; oo++)
#pragma unroll
                    for (int xq = 0; xq < 6; xq++)
                        acc[oo][xq] = fmaf(w4[oo], a[xq + j], acc[oo][xq]);
            }
        }
    }
    size_t obase = (size_t)blk * 4608 + (size_t)ob * 36 + y * 6;
#pragma unroll
    for (int oo = 0; oo < 4; oo++) {
        float bv = b2[ob + oo];
        float* dst = psp2c + obase + oo * 36;
#pragma unroll
        for (int xq = 0; xq < 6; xq++)
            dst[xq] = __fadd_rn(acc[oo][xq], bv);
    }
}

// ---------------------------------------------------------------------------
// K3: LIF2 + AvgPool(2), fp32 states (12 planes x 73728 in st2), chunk.
// pc: fp32 [b*TC+tl][1152] (exact multiples of 0.25).
// ---------------------------------------------------------------------------
__global__ __launch_bounds__(256) void k_lif2pool(const float* __restrict__ psp2c,
                                                  float* __restrict__ pc,
                                                  float* __restrict__ st2,
                                                  int TC, int first) {
    int idx = blockIdx.x * 256 + threadIdx.x;   // 73728
    int px = idx % 3; int r = idx / 3; int py = r % 3; r /= 3;
    int o = r & 127, b = r >> 7;
    const float* pb = psp2c + (size_t)b * TC * 4608 + o * 36;
    float* pd = pc + (size_t)b * TC * 1152 + o * 9 + py * 3 + px;
    int off0 = (2 * py) * 6 + 2 * px, off1 = off0 + 6;
    float c0, c1, c2, c3, v0, v1, v2, v3, s0, s1, s2, s3;
    if (first) {
        c0 = c1 = c2 = c3 = v0 = v1 = v2 = v3 = s0 = s1 = s2 = s3 = 0.f;
    } else {
        c0 = st2[idx];              c1 = st2[73728 + idx];
        c2 = st2[147456 + idx];     c3 = st2[221184 + idx];
        v0 = st2[294912 + idx];     v1 = st2[368640 + idx];
        v2 = st2[442368 + idx];     v3 = st2[516096 + idx];
        s0 = st2[589824 + idx];     s1 = st2[663552 + idx];
        s2 = st2[737280 + idx];     s3 = st2[811008 + idx];
    }
    for (int tl = 0; tl < TC; tl++) {
        const float* pt = pb + (size_t)tl * 4608;
        float2 ra = *(const float2*)(pt + off0);
        float2 rb = *(const float2*)(pt + off1);
        lif32(ra.x, c0, v0, s0);
        lif32(ra.y, c1, v1, s1);
        lif32(rb.x, c2, v2, s2);
        lif32(rb.y, c3, v3, s3);
        // sum of 0/1 values: exact in any order; *0.25 exact
        pd[(size_t)tl * 1152] = __fmul_rn(0.25f, __fadd_rn(__fadd_rn(__fadd_rn(s0, s1), s2), s3));
    }
    st2[idx] = c0;           st2[73728 + idx] = c1;
    st2[147456 + idx] = c2;  st2[221184 + idx] = c3;
    st2[294912 + idx] = v0;  st2[368640 + idx] = v1;
    st2[442368 + idx] = v2;  st2[516096 + idx] = v3;
    st2[589824 + idx] = s0;  st2[663552 + idx] = s1;
    st2[737280 + idx] = s2;  st2[811008 + idx] = s3;
}

// ---------------------------------------------------------------------------
// K4: conv3 GEMM rows x 256, K=1152 (ascending, sequential fp32 fmaf),
// K-chunked LDS (16x288 fp32). Epilogue: +bias unfused.
// ---------------------------------------------------------------------------
__global__ __launch_bounds__(256) void k_conv3(const float* __restrict__ pc,
                                               const float* __restrict__ w3T,
                                               const float* __restrict__ b3,
                                               float* __restrict__ psp3c) {
    __shared__ float a_s[16 * 288];
    int row0 = blockIdx.x * 16;
    int tid = threadIdx.x;
    int oq = tid & 63, mg = tid >> 6;
    float acc[4][4];
#pragma unroll
    for (int oo = 0; oo < 4; oo++)
#pragma unroll
        for (int mi = 0; mi < 4; mi++) acc[oo][mi] = 0.f;
    for (int kc = 0; kc < 1152; kc += 288) {
        __syncthreads();
        for (int idx = tid; idx < 16 * 288; idx += 256) {
            int m = idx / 288, k = idx - m * 288;
            a_s[idx] = pc[(size_t)(row0 + m) * 1152 + kc + k];
        }
        __syncthreads();
        for (int k = 0; k < 288; k++) {
            float4 wv = *(const float4*)&w3T[(size_t)(kc + k) * 256 + (oq << 2)];
            float w4[4] = {wv.x, wv.y, wv.z, wv.w};
            float am[4];
#pragma unroll
            for (int mi = 0; mi < 4; mi++) am[mi] = a_s[(mg * 4 + mi) * 288 + k];
#pragma unroll
            for (int oo = 0; oo < 4; oo++)
#pragma unroll
                for (int mi = 0; mi < 4; mi++)
                    acc[oo][mi] = fmaf(w4[oo], am[mi], acc[oo][mi]);
        }
    }
#pragma unroll
    for (int mi = 0; mi < 4; mi++) {
        float* dst = psp3c + (size_t)(row0 + mg * 4 + mi) * 256 + (oq << 2);
#pragma unroll
        for (int oo = 0; oo < 4; oo++)
            dst[oo] = __fadd_rn(acc[oo][mi], b3[(oq << 2) + oo]);
    }
}

// ---------------------------------------------------------------------------
// K5: LIF3 scan on chunk, fp32 states (st3), writes u8 s3u8[b][t][256].
// ---------------------------------------------------------------------------
__global__ __launch_bounds__(256) void k_scan3(const float* __restrict__ psp3c,
                                               unsigned char* __restrict__ s3u8,
                                               float* __restrict__ st3,
                                               int t0, int TC, int first) {
    int idx = blockIdx.x * 256 + threadIdx.x;   // 16384
    int b = idx >> 8, n = idx & 255;
    float cur, volt, spk;
    if (first) { cur = 0.f; volt = 0.f; spk = 0.f; }
    else { cur = st3[idx]; volt = st3[16384 + idx]; spk = st3[32768 + idx]; }
    for (int tl = 0; tl < TC; tl++) {
        lif32(psp3c[(size_t)(b * TC + tl) * 256 + n], cur, volt, spk);
        s3u8[((size_t)b * T_ + t0 + tl) * 256 + n] = (unsigned char)spk;
    }
    st3[idx] = cur; st3[16384 + idx] = volt; st3[32768 + idx] = spk;
}

// ---------------------------------------------------------------------------
// K6: temporal conv, back-end chunk TCB=50. Per tap: sequential fp32 dot
// (k=0..255) -> +bias (unfused) -> gated sequential psum (numpy order).
// ---------------------------------------------------------------------------
__global__ __launch_bounds__(256) void k_tc(const unsigned char* __restrict__ s3u8,
                                            const float* __restrict__ tcT,
                                            const float* __restrict__ tc_b,
                                            float* __restrict__ ptcc, int t0) {
    __shared__ float a_s[16 * 256];
    int crow0 = blockIdx.x * 16;
    int tid = threadIdx.x;
    int oq = tid & 63, mg = tid >> 6;
    float psum[4][4];
#pragma unroll
    for (int oo = 0; oo < 4; oo++)
#pragma unroll
        for (int mi = 0; mi < 4; mi++) psum[oo][mi] = 0.f;
    for (int tap = 0; tap < 3; tap++) {
        __syncthreads();
        for (int idx = tid; idx < 16 * 256; idx += 256) {
            int m = idx >> 8, k = idx & 255;
            int crow = crow0 + m;
            int b = crow / TCB_, tl = crow - b * TCB_;
            int t = t0 + tl;
            float v = 0.f;
            if (t >= tap) v = (float)s3u8[((size_t)b * T_ + t - tap) * 256 + k];
            a_s[idx] = v;
        }
        __syncthreads();
        float acc[4][4];
#pragma unroll
        for (int oo = 0; oo < 4; oo++)
#pragma unroll
            for (int mi = 0; mi < 4; mi++) acc[oo][mi] = 0.f;
        const float* wbase = tcT + (size_t)tap * 65536 + (oq << 2);
        for (int k = 0; k < 256; k++) {
            float4 wv = *(const float4*)(wbase + (size_t)k * 256);
            float w4[4] = {wv.x, wv.y, wv.z, wv.w};
            float am[4];
#pragma unroll
            for (int mi = 0; mi < 4; mi++) am[mi] = a_s[(mg * 4 + mi) * 256 + k];
#pragma unroll
            for (int oo = 0; oo < 4; oo++)
#pragma unroll
                for (int mi = 0; mi < 4; mi++)
                    acc[oo][mi] = fmaf(w4[oo], am[mi], acc[oo][mi]);
        }
#pragma unroll
        for (int mi = 0; mi < 4; mi++) {
            int crow = crow0 + mg * 4 + mi;
            int b = crow / TCB_, tl = crow - b * TCB_;
            int t = t0 + tl;
            float g = (t >= tap) ? 1.0f : 0.0f;
#pragma unroll
            for (int oo = 0; oo < 4; oo++) {
                int oc = (oq << 2) + oo;
                float tap_f = __fadd_rn(acc[oo][mi], tc_b[tap * 256 + oc]);
                psum[oo][mi] = __fadd_rn(psum[oo][mi], __fmul_rn(g, tap_f));
            }
        }
    }
#pragma unroll
    for (int mi = 0; mi < 4; mi++) {
        int crow = crow0 + mg * 4 + mi;
        float* dst = ptcc + (size_t)crow * 256 + (oq << 2);
#pragma unroll
        for (int oo = 0; oo < 4; oo++) dst[oo] = psum[oo][mi];
    }
}

// ---------------------------------------------------------------------------
// K7: LIF scan for tc layer, back-end chunk, fp32 states st_tc.
// ---------------------------------------------------------------------------
__global__ __launch_bounds__(256) void k_scan_tc(const float* __restrict__ ptcc,
                                                 unsigned char* __restrict__ s_tc8,
                                                 float* __restrict__ st_tc,
                                                 int t0, int first) {
    int idx = blockIdx.x * 256 + threadIdx.x;   // 16384
    int b = idx >> 8, n = idx & 255;
    float cur, volt, spk;
    if (first) { cur = 0.f; volt = 0.f; spk = 0.f; }
    else { cur = st_tc[idx]; volt = st_tc[16384 + idx]; spk = st_tc[32768 + idx]; }
    for (int tl = 0; tl < TCB_; tl++) {
        lif32(ptcc[(size_t)(b * TCB_ + tl) * 256 + n], cur, volt, spk);
        s_tc8[((size_t)b * T_ + t0 + tl) * 256 + n] = (unsigned char)spk;
    }
    st_tc[idx] = cur; st_tc[16384 + idx] = volt; st_tc[32768 + idx] = spk;
}

// ---------------------------------------------------------------------------
// K8: recurrent layer. WG per batch element; prev spikes in LDS (double-
// buffered, ONE barrier/step). Inner loop BRANCHLESS: acc + (sv?w:0) is
// bit-identical to skipping zeros (x+0==x, acc starts +0), but lets the
// compiler pipeline all 256 independent loads. psp = (s_tc + mat) + rec_b
// unfused (numpy order).
// ---------------------------------------------------------------------------
__global__ __launch_bounds__(256) void k_rec(const unsigned char* __restrict__ s_tc8,
                                             const float* __restrict__ recT,
                                             const float* __restrict__ rec_b,
                                             unsigned char* __restrict__ s_r8) {
    __shared__ float spk_s[2][256];
    int b = blockIdx.x, o = threadIdx.x;
    spk_s[0][o] = 0.f;
    float cur = 0.f, volt = 0.f, spk = 0.f;
    float rb = rec_b[o];
    __syncthreads();
    int p = 0;
    for (int t = 0; t < T_; t++) {
        const float* sp = spk_s[p];
        float acc = 0.f;
#pragma unroll 16
        for (int k = 0; k < 256; k++) {
            float sv = sp[k];
            float w = recT[(size_t)k * 256 + o];
            acc = __fadd_rn(acc, (sv != 0.f) ? w : 0.0f);
        }
        float stc = (float)s_tc8[((size_t)b * T_ + t) * 256 + o];
        float psp = __fadd_rn(__fadd_rn(stc, acc), rb);
        lif32(psp, cur, volt, spk);
        s_r8[((size_t)b * T_ + t) * 256 + o] = (unsigned char)spk;
        spk_s[p ^ 1][o] = spk;      // write other buffer while peers read p
        __syncthreads();            // single barrier: publish before next read
        p ^= 1;
    }
}

// ---------------------------------------------------------------------------
// K9: fc1 GEMM, back-end chunk. Sequential fp32 fmaf k=0..255; +bias after.
// ---------------------------------------------------------------------------
__global__ __launch_bounds__(256) void k_fc1(const unsigned char* __restrict__ s_r8,
                                             const float* __restrict__ fc1T,
                                             const float* __restrict__ fc1_b,
                                             float* __restrict__ pfc, int t0) {
    __shared__ float a_s[16 * 256];
    int crow0 = blockIdx.x * 16;
    int tid = threadIdx.x;
    int oq = tid & 31, mg = tid >> 5;           // 8 m-groups, tile 2m
    float acc[4][2];
#pragma unroll
    for (int oo = 0; oo < 4; oo++) { acc[oo][0] = 0.f; acc[oo][1] = 0.f; }
    for (int idx = tid; idx < 16 * 256; idx += 256) {
        int m = idx >> 8, k = idx & 255;
        int crow = crow0 + m;
        int b = crow / TCB_, tl = crow - b * TCB_;
        a_s[idx] = (float)s_r8[((size_t)b * T_ + t0 + tl) * 256 + k];
    }
    __syncthreads();
    for (int k = 0; k < 256; k++) {
        float4 wv = *(const float4*)&fc1T[(size_t)k * 128 + (oq << 2)];
        float w4[4] = {wv.x, wv.y, wv.z, wv.w};
        float a0 = a_s[(mg * 2 + 0) * 256 + k];
        float a1 = a_s[(mg * 2 + 1) * 256 + k];
#pragma unroll
        for (int oo = 0; oo < 4; oo++) {
            acc[oo][0] = fmaf(w4[oo], a0, acc[oo][0]);
            acc[oo][1] = fmaf(w4[oo], a1, acc[oo][1]);
        }
    }
#pragma unroll
    for (int mi = 0; mi < 2; mi++) {
        float* dst = pfc + (size_t)(crow0 + mg * 2 + mi) * 128 + (oq << 2);
#pragma unroll
        for (int oo = 0; oo < 4; oo++)
            dst[oo] = __fadd_rn(acc[oo][mi], fc1_b[(oq << 2) + oo]);
    }
}

// ---------------------------------------------------------------------------
// K10: LIF scan for fc1 layer, back-end chunk, fp32 states st_f.
// ---------------------------------------------------------------------------
__global__ __launch_bounds__(256) void k_scan_f(const float* __restrict__ pfc,
                                                unsigned char* __restrict__ s_f8,
                                                float* __restrict__ st_f,
                                                int t0, int first) {
    int idx = blockIdx.x * 256 + threadIdx.x;   // 8192
    int b = idx >> 7, n = idx & 127;
    float cur, volt, spk;
    if (first) { cur = 0.f; volt = 0.f; spk = 0.f; }
    else { cur = st_f[idx]; volt = st_f[8192 + idx]; spk = st_f[16384 + idx]; }
    for (int tl = 0; tl < TCB_; tl++) {
        lif32(pfc[(size_t)(b * TCB_ + tl) * 128 + n], cur, volt, spk);
        s_f8[((size_t)b * T_ + t0 + tl) * 128 + n] = (unsigned char)spk;
    }
    st_f[idx] = cur; st_f[8192 + idx] = volt; st_f[16384 + idx] = spk;
}

// ---------------------------------------------------------------------------
// K11: out[b,:] = fc2_w @ (sum_t ts[t]*s_f[b,t,:]) — linear head, fp64
// accumulation (differences ~1e-7 are far below the bf16 floor).
// ---------------------------------------------------------------------------
__global__ __launch_bounds__(128) void k_final(const unsigned char* __restrict__ s_f8,
                                               const float* __restrict__ ts,
                                               const float* __restrict__ fc2,
                                               float* __restrict__ out) {
    __shared__ double q_s[128];
    int b = blockIdx.x, k = threadIdx.x;
    double q = 0.0;
    const unsigned char* sf = s_f8 + (size_t)b * T_ * 128 + k;
    for (int t = 0; t < T_; t++) q = fma((double)ts[t], (double)sf[(size_t)t * 128], q);
    q_s[k] = q;
    __syncthreads();
    if (k < 2) {
        double o = 0.0;
        for (int kk = 0; kk < 128; kk++) o = fma((double)fc2[k * 128 + kk], q_s[kk], o);
        out[b * 2 + k] = (float)o;
    }
}

// ---------------------------------------------------------------------------
extern "C" void kernel_launch(void* const* d_in, const int* in_sizes, int n_in,
                              void* d_out, int out_size, void* d_ws, size_t ws_size,
                              hipStream_t stream) {
    const float* x       = (const float*)d_in[0];
    const float* conv1_w = (const float*)d_in[1];
    const float* conv1_b = (const float*)d_in[2];
    const float* conv2_w = (const float*)d_in[3];
    const float* conv2_b = (const float*)d_in[4];
    const float* conv3_w = (const float*)d_in[5];
    const float* conv3_b = (const float*)d_in[6];
    const float* tc_w    = (const float*)d_in[7];
    const float* tc_b    = (const float*)d_in[8];
    const float* rec_w   = (const float*)d_in[9];
    const float* rec_b   = (const float*)d_in[10];
    const float* fc1_w   = (const float*)d_in[11];
    const float* fc1_b   = (const float*)d_in[12];
    const float* fc2_w   = (const float*)d_in[13];
    const float* ts_w    = (const float*)d_in[14];
    float* out = (float*)d_out;
    (void)in_sizes; (void)n_in; (void)out_size;

    // ---- persistent region: 21,299,200 B ----
    char* base = (char*)d_ws;
    float* w2T  = (float*)(base + 0);           //   294,912 B
    float* w3T  = (float*)(base + 294912);      // 1,179,648 B
    float* tcT  = (float*)(base + 1474560);     //   786,432 B
    float* recT = (float*)(base + 2260992);     //   262,144 B
    float* fc1T = (float*)(base + 2523136);     //   131,072 B
    float* st1  = (float*)(base + 2654208);     // 3,145,728 B
    float* st2  = (float*)(base + 5799936);     // 3,538,944 B
    float* st3  = (float*)(base + 9338880);     //   196,608 B
    float* st_tc= (float*)(base + 9535488);     //   196,608 B
    float* st_f = (float*)(base + 9732096);     //    98,304 B
    unsigned char* s3u8  = (unsigned char*)(base + 9830400);   // 3,276,800 B
    unsigned char* s_tc8 = (unsigned char*)(base + 13107200);  // 3,276,800 B
    unsigned char* s_r8  = (unsigned char*)(base + 16384000);  // 3,276,800 B
    unsigned char* s_f8  = (unsigned char*)(base + 19660800);  // 1,638,400 B

    // ---- chunked scratch region, TCF chosen from ws_size (graph-safe) ----
    const size_t PERS = 21299200;
    const size_t PER_T = 1802240;   // bytes per front-end timestep (B=64)
    int TCF;
    if      (ws_size >= PERS + 40 * PER_T) TCF = 40;
    else if (ws_size >= PERS + 20 * PER_T) TCF = 20;
    else if (ws_size >= PERS +  8 * PER_T) TCF = 8;   // 35.7 MB — proven fit
    else                                   TCF = 4;
    int NCH = T_ / TCF;
    char* cb = base + PERS;
    float* psp2c = (float*)(cb);                                      // TCF*1,179,648 B
    float* psp3c = (float*)(cb + (size_t)TCF * 1179648);              // TCF*65,536 B
    float* pc    = (float*)(cb + (size_t)TCF * (1179648 + 65536));    // TCF*294,912 B
    unsigned char* s1c = (unsigned char*)(cb + (size_t)TCF * (1179648 + 65536 + 294912)); // TCF*262,144 B
    // back-end chunk buffers alias the front-end scratch (dead by then)
    float* ptcc = (float*)(cb);              // 3,276,800 B
    float* pfc  = (float*)(cb + 3276800);    // 1,638,400 B

    k_setup<<<2592, 256, 0, stream>>>(conv2_w, conv3_w, tc_w, rec_w, fc1_w,
                                      w2T, w3T, tcT, recT, fc1T);
    for (int ch = 0; ch < NCH; ch++) {
        int t0 = ch * TCF;
        int first = (ch == 0) ? 1 : 0;
        k_conv1<<<1024, 256, 0, stream>>>(x, conv1_w, conv1_b, s1c, st1, t0, TCF, first);
        k_conv2<<<B_ * TCF, 192, 0, stream>>>(s1c, w2T, conv2_b, psp2c);
        k_lif2pool<<<288, 256, 0, stream>>>(psp2c, pc, st2, TCF, first);
        k_conv3<<<B_ * TCF / 16, 256, 0, stream>>>(pc, w3T, conv3_b, psp3c);
        k_scan3<<<64, 256, 0, stream>>>(psp3c, s3u8, st3, t0, TCF, first);
    }
    for (int bc = 0; bc < T_ / TCB_; bc++) {
        int t0 = bc * TCB_;
        k_tc<<<B_ * TCB_ / 16, 256, 0, stream>>>(s3u8, tcT, tc_b, ptcc, t0);
        k_scan_tc<<<64, 256, 0, stream>>>(ptcc, s_tc8, st_tc, t0, (bc == 0) ? 1 : 0);
    }
    k_rec<<<64, 256, 0, stream>>>(s_tc8, recT, rec_b, s_r8);
    for (int bc = 0; bc < T_ / TCB_; bc++) {
        int t0 = bc * TCB_;
        k_fc1<<<B_ * TCB_ / 16, 256, 0, stream>>>(s_r8, fc1T, fc1_b, pfc, t0);
        k_scan_f<<<32, 256, 0, stream>>>(pfc, s_f8, st_f, t0, (bc == 0) ? 1 : 0);
    }
    k_final<<<64, 128, 0, stream>>>(s_f8, ts_w, fc2_w, out);
}